// Round 1
// baseline (546.382 us; speedup 1.0000x reference)
//
#include <hip/hip_runtime.h>

// Problem constants (fixed by reference): B=4,H=16,S=1024,D=64
constexpr int SEQ = 1024;
constexpr int DH  = 64;
constexpr int QR  = 32;    // q rows per block
constexpr int KT  = 128;   // key tile
constexpr int SP  = 1028;  // fp32 score row stride (pad keeps 16B align + rotates banks)
constexpr int KS  = 72;    // bf16 row stride for sQ/sK (64+8 -> 2-way-free b128 reads)
constexpr int VS  = 136;   // bf16 row stride for sVt (128+8)

typedef __bf16 bf16x8 __attribute__((ext_vector_type(8)));
typedef __bf16 bf16x4 __attribute__((ext_vector_type(4)));
typedef float  f32x4  __attribute__((ext_vector_type(4)));

__global__ __launch_bounds__(256)
void attn_fused_kernel(const float* __restrict__ Q, const float* __restrict__ K,
                       const float* __restrict__ V, const float* __restrict__ bias,
                       float* __restrict__ out, float* __restrict__ attn)
{
    __shared__ float  sS[QR * SP];        // 131,584 B: fp32 scores/probs strip
    __shared__ __bf16 sQ[QR * KS];        //   4,608 B
    __shared__ __bf16 sKV[KT * KS];       //  18,432 B: K tile (phase1) / V^T tile (phase3, 64*136=8704 fits)

    const int tid  = threadIdx.x;
    const int w    = tid >> 6;            // wave 0..3
    const int l    = tid & 63;
    const int head = blockIdx.x >> 5;     // 0..63  (b*H + h)
    const int q0   = (blockIdx.x & 31) * QR;
    const float scale = 0.125f;           // 1/sqrt(64)

    const float* Qh = Q + (size_t)head * SEQ * DH;
    const float* Kh = K + (size_t)head * SEQ * DH;
    const float* Vh = V + (size_t)head * SEQ * DH;
    float* outh  = out  + (size_t)head * SEQ * DH;
    float* attnh = attn + (size_t)head * SEQ * SEQ;

    // ---- stage Q: 32x64 f32 -> bf16 LDS (stride KS) ----
    for (int i = 0; i < 2; ++i) {
        int u = tid + 256 * i;            // 0..511 units of float4
        int row = u >> 4, dg = u & 15;
        f32x4 v = *(const f32x4*)(Qh + (q0 + row) * DH + dg * 4);
        bf16x4 b;
        b[0] = (__bf16)v[0]; b[1] = (__bf16)v[1]; b[2] = (__bf16)v[2]; b[3] = (__bf16)v[3];
        *(bf16x4*)(sQ + row * KS + dg * 4) = b;
    }

    // ---- Phase 1: scores = scale * Q K^T  (written to sS) ----
    const int qt  = w & 1;                // q subtile (16 rows)
    const int ntb = (w >> 1) * 4;         // 4 key subtiles of 16 per wave
    const int lm  = l & 15;
    const int lq  = l >> 4;               // quad 0..3
    for (int kt = 0; kt < SEQ / KT; ++kt) {
        __syncthreads();                  // prior reads of sKV done (also covers Q staging on iter 0)
        for (int i = 0; i < 8; ++i) {     // stage K tile 128x64 f32 -> bf16
            int u = tid + 256 * i;        // 0..2047
            int row = u >> 4, dg = u & 15;
            f32x4 v = *(const f32x4*)(Kh + (kt * KT + row) * DH + dg * 4);
            bf16x4 b;
            b[0] = (__bf16)v[0]; b[1] = (__bf16)v[1]; b[2] = (__bf16)v[2]; b[3] = (__bf16)v[3];
            *(bf16x4*)(sKV + row * KS + dg * 4) = b;
        }
        __syncthreads();
        f32x4 acc[4] = {{0.f,0.f,0.f,0.f},{0.f,0.f,0.f,0.f},{0.f,0.f,0.f,0.f},{0.f,0.f,0.f,0.f}};
        for (int ks = 0; ks < 2; ++ks) {  // contraction over d=64 in two k=32 steps
            bf16x8 afrag = *(const bf16x8*)(sQ + (qt * 16 + lm) * KS + ks * 32 + lq * 8);
            for (int c = 0; c < 4; ++c) {
                bf16x8 bfrag = *(const bf16x8*)(sKV + ((ntb + c) * 16 + lm) * KS + ks * 32 + lq * 8);
                acc[c] = __builtin_amdgcn_mfma_f32_16x16x32_bf16(afrag, bfrag, acc[c], 0, 0, 0);
            }
        }
        int row0 = qt * 16 + lq * 4;
        int colbase = kt * KT + lm;
        for (int c = 0; c < 4; ++c)
            for (int r = 0; r < 4; ++r)
                sS[(row0 + r) * SP + colbase + (ntb + c) * 16] = acc[c][r] * scale;
    }
    __syncthreads();

    // ---- Phase 2: + bias, softmax over k, write attn weights ----
    {
        const int r = tid >> 3;                 // row 0..31
        const int j = tid & 7;                  // 8 threads per row
        const int rot = ((j + r) & 7) * 4;      // bank-rotated, coalescing-preserving
        float* rowp = sS + r * SP;
        const float* brow = bias + (size_t)(q0 + r) * SEQ;
        float mx = -1e30f;
        for (int i = 0; i < 32; ++i) {
            int c = rot + 32 * i;
            f32x4 x = *(f32x4*)(rowp + c);
            f32x4 b = *(const f32x4*)(brow + c);
            x += b;
            *(f32x4*)(rowp + c) = x;
            mx = fmaxf(mx, fmaxf(fmaxf(x[0], x[1]), fmaxf(x[2], x[3])));
        }
        for (int off = 1; off < 8; off <<= 1)
            mx = fmaxf(mx, __shfl_xor(mx, off, 8));
        float sum = 0.f;
        for (int i = 0; i < 32; ++i) {
            int c = rot + 32 * i;
            f32x4 x = *(f32x4*)(rowp + c);
            x[0] = __expf(x[0] - mx); x[1] = __expf(x[1] - mx);
            x[2] = __expf(x[2] - mx); x[3] = __expf(x[3] - mx);
            *(f32x4*)(rowp + c) = x;
            sum += x[0] + x[1] + x[2] + x[3];
        }
        for (int off = 1; off < 8; off <<= 1)
            sum += __shfl_xor(sum, off, 8);
        float inv = 1.0f / sum;
        float* arow = attnh + (size_t)(q0 + r) * SEQ;
        for (int i = 0; i < 32; ++i) {
            int c = rot + 32 * i;
            f32x4 x = *(f32x4*)(rowp + c);
            x *= inv;
            *(f32x4*)(rowp + c) = x;       // keep normalized P for phase 3
            *(f32x4*)(arow + c) = x;       // attn_weights output
        }
    }
    __syncthreads();

    // ---- Phase 3: out = P V  (V^T staged in LDS) ----
    const int dtb = (w >> 1) * 2;          // 2 d-subtiles of 16 per wave
    f32x4 oacc[2] = {{0.f,0.f,0.f,0.f},{0.f,0.f,0.f,0.f}};
    for (int kt = 0; kt < SEQ / KT; ++kt) {
        __syncthreads();                   // prior reads of sKV done
        for (int i = 0; i < 2; ++i) {      // stage V^T: 4x4 micro-transpose per unit
            int u = tid + 256 * i;         // 512 units: 32 kb x 16 db
            int kb = u & 31, db = u >> 5;
            int k0 = kb * 4, d0 = db * 4;
            f32x4 v0 = *(const f32x4*)(Vh + (size_t)(kt * KT + k0 + 0) * DH + d0);
            f32x4 v1 = *(const f32x4*)(Vh + (size_t)(kt * KT + k0 + 1) * DH + d0);
            f32x4 v2 = *(const f32x4*)(Vh + (size_t)(kt * KT + k0 + 2) * DH + d0);
            f32x4 v3 = *(const f32x4*)(Vh + (size_t)(kt * KT + k0 + 3) * DH + d0);
            for (int jj = 0; jj < 4; ++jj) {
                bf16x4 b;
                b[0] = (__bf16)v0[jj]; b[1] = (__bf16)v1[jj];
                b[2] = (__bf16)v2[jj]; b[3] = (__bf16)v3[jj];
                *(bf16x4*)(sKV + (d0 + jj) * VS + k0) = b;
            }
        }
        __syncthreads();
        for (int ks = 0; ks < 4; ++ks) {   // contraction over this key tile (128 = 4 x 32)
            int kk = kt * KT + ks * 32 + lq * 8;
            f32x4 plo = *(const f32x4*)(sS + (qt * 16 + lm) * SP + kk);
            f32x4 phi = *(const f32x4*)(sS + (qt * 16 + lm) * SP + kk + 4);
            bf16x8 afrag;
            afrag[0] = (__bf16)plo[0]; afrag[1] = (__bf16)plo[1];
            afrag[2] = (__bf16)plo[2]; afrag[3] = (__bf16)plo[3];
            afrag[4] = (__bf16)phi[0]; afrag[5] = (__bf16)phi[1];
            afrag[6] = (__bf16)phi[2]; afrag[7] = (__bf16)phi[3];
            for (int c = 0; c < 2; ++c) {
                bf16x8 bfrag = *(const bf16x8*)(sKV + ((dtb + c) * 16 + lm) * VS + ks * 32 + lq * 8);
                oacc[c] = __builtin_amdgcn_mfma_f32_16x16x32_bf16(afrag, bfrag, oacc[c], 0, 0, 0);
            }
        }
    }
    {
        int row0 = qt * 16 + lq * 4;
        for (int c = 0; c < 2; ++c)
            for (int r = 0; r < 4; ++r)
                outh[(size_t)(q0 + row0 + r) * DH + (dtb + c) * 16 + lm] = oacc[c][r];
    }
}

extern "C" void kernel_launch(void* const* d_in, const int* in_sizes, int n_in,
                              void* d_out, int out_size, void* d_ws, size_t ws_size,
                              hipStream_t stream) {
    const float* Q    = (const float*)d_in[0];
    const float* K    = (const float*)d_in[1];
    const float* V    = (const float*)d_in[2];
    const float* bias = (const float*)d_in[3];
    float* out  = (float*)d_out;                      // [4,16,1024,64] = 4,194,304 floats
    float* attn = (float*)d_out + 4 * 16 * 1024 * 64; // [4,16,1024,1024]
    dim3 grid(64 * (SEQ / QR));   // 64 heads x 32 q-tiles = 2048 blocks
    dim3 block(256);
    attn_fused_kernel<<<grid, block, 0, stream>>>(Q, K, V, bias, out, attn);
}

// Round 2
// 472.601 us; speedup vs baseline: 1.1561x; 1.1561x over previous
//
#include <hip/hip_runtime.h>

// B=4,H=16,S=1024,D=64. Outputs: out [64,1024,64] fp32 then attn [64,1024,1024] fp32.
constexpr int SEQ = 1024;
constexpr int DH  = 64;
constexpr int QR  = 32;    // q rows per block
constexpr int KT  = 128;   // key tile
constexpr int KS  = 72;    // bf16 row stride for sQ/sK (64+8; 144 B = 16*9, keeps b128 align)
constexpr int VS  = 136;   // bf16 row stride for sV^T (128+8; 272 B = 16*17)
constexpr int PS  = 136;   // bf16 row stride for sP

typedef __bf16 bf16x8 __attribute__((ext_vector_type(8)));
typedef __bf16 bf16x4 __attribute__((ext_vector_type(4)));
typedef float  f32x4  __attribute__((ext_vector_type(4)));

__global__ __launch_bounds__(256, 3)
void attn_flash_kernel(const float* __restrict__ Q, const float* __restrict__ K,
                       const float* __restrict__ V, const float* __restrict__ bias,
                       float* __restrict__ out, float* __restrict__ attn)
{
    __shared__ __bf16 sQ[QR * KS];     //  4,608 B
    __shared__ __bf16 sK[KT * KS];     // 18,432 B
    __shared__ __bf16 sV[DH * VS];     // 17,408 B  (V^T for the current key tile)
    __shared__ __bf16 sP[QR * PS];     //  8,704 B  (P tile, C-layout -> A-layout transpose)
    __shared__ float  sRM[2][QR];      // per col-half running max
    __shared__ float  sRL[2][QR];      // per col-half running sum
    // total ~49.9 KB -> 3 blocks/CU

    const int tid  = threadIdx.x;
    const int w    = tid >> 6;
    const int l    = tid & 63;
    const int qt   = w & 1;            // q subtile (16 rows)
    const int ch   = w >> 1;           // column half (64 keys of the 128 tile)
    const int lm   = l & 15;
    const int lq   = l >> 4;
    const int head = blockIdx.x >> 5;
    const int q0   = (blockIdx.x & 31) * QR;
    const float scale = 0.125f;

    const float* Qh = Q + (size_t)head * SEQ * DH;
    const float* Kh = K + (size_t)head * SEQ * DH;
    const float* Vh = V + (size_t)head * SEQ * DH;
    float* outh  = out  + (size_t)head * SEQ * DH;
    float* attnh = attn + (size_t)head * SEQ * SEQ;

    // ---- stage Q: 32x64 f32 -> bf16 ----
    #pragma unroll
    for (int i = 0; i < 2; ++i) {
        int u = tid + 256 * i;
        int row = u >> 4, dg = u & 15;
        f32x4 v = *(const f32x4*)(Qh + (size_t)(q0 + row) * DH + dg * 4);
        bf16x4 b;
        b[0] = (__bf16)v[0]; b[1] = (__bf16)v[1]; b[2] = (__bf16)v[2]; b[3] = (__bf16)v[3];
        *(bf16x4*)(sQ + row * KS + dg * 4) = b;
    }

    const int rowg = q0 + qt * 16 + lq * 4;   // first of 4 q rows this lane covers in C-layout

    // =================== Pass A: running (m,l) only ===================
    float m_run[4], l_run[4];
    #pragma unroll
    for (int r = 0; r < 4; ++r) { m_run[r] = -1e30f; l_run[r] = 0.f; }

    for (int kt = 0; kt < SEQ / KT; ++kt) {
        __syncthreads();
        #pragma unroll
        for (int i = 0; i < 8; ++i) {          // stage K tile 128x64
            int u = tid + 256 * i;
            int row = u >> 4, dg = u & 15;
            f32x4 v = *(const f32x4*)(Kh + (size_t)(kt * KT + row) * DH + dg * 4);
            bf16x4 b;
            b[0] = (__bf16)v[0]; b[1] = (__bf16)v[1]; b[2] = (__bf16)v[2]; b[3] = (__bf16)v[3];
            *(bf16x4*)(sK + row * KS + dg * 4) = b;
        }
        __syncthreads();

        f32x4 acc[4] = {{0,0,0,0},{0,0,0,0},{0,0,0,0},{0,0,0,0}};
        #pragma unroll
        for (int ks = 0; ks < 2; ++ks) {
            bf16x8 afrag = *(const bf16x8*)(sQ + (qt * 16 + lm) * KS + ks * 32 + lq * 8);
            #pragma unroll
            for (int c = 0; c < 4; ++c) {
                bf16x8 bfrag = *(const bf16x8*)(sK + ((ch * 4 + c) * 16 + lm) * KS + ks * 32 + lq * 8);
                acc[c] = __builtin_amdgcn_mfma_f32_16x16x32_bf16(afrag, bfrag, acc[c], 0, 0, 0);
            }
        }
        const int colg = kt * KT + ch * 64 + lm;
        #pragma unroll
        for (int r = 0; r < 4; ++r) {
            const float* brow = bias + (size_t)(rowg + r) * SEQ + colg;
            float x0 = acc[0][r] * scale + brow[0];
            float x1 = acc[1][r] * scale + brow[16];
            float x2 = acc[2][r] * scale + brow[32];
            float x3 = acc[3][r] * scale + brow[48];
            float tm = fmaxf(fmaxf(x0, x1), fmaxf(x2, x3));
            #pragma unroll
            for (int off = 1; off < 16; off <<= 1)
                tm = fmaxf(tm, __shfl_xor(tm, off));
            float mn = fmaxf(m_run[r], tm);
            float corr = __expf(m_run[r] - mn);
            float s = __expf(x0 - mn) + __expf(x1 - mn) + __expf(x2 - mn) + __expf(x3 - mn);
            #pragma unroll
            for (int off = 1; off < 16; off <<= 1)
                s += __shfl_xor(s, off);
            l_run[r] = l_run[r] * corr + s;
            m_run[r] = mn;
        }
    }

    // ---- combine the two column halves ----
    if (lm == 0) {
        #pragma unroll
        for (int r = 0; r < 4; ++r) {
            sRM[ch][qt * 16 + lq * 4 + r] = m_run[r];
            sRL[ch][qt * 16 + lq * 4 + r] = l_run[r];
        }
    }
    __syncthreads();
    float mfin[4], linv[4];
    #pragma unroll
    for (int r = 0; r < 4; ++r) {
        int row = qt * 16 + lq * 4 + r;
        float m0 = sRM[0][row], m1 = sRM[1][row];
        float m  = fmaxf(m0, m1);
        float lsum = sRL[0][row] * __expf(m0 - m) + sRL[1][row] * __expf(m1 - m);
        mfin[r] = m;
        linv[r] = 1.0f / lsum;
    }

    // =================== Pass B: recompute, write attn, P*V ===================
    const int dtb = ch * 2;                    // 2 d-subtiles of 16 per wave
    f32x4 oacc[2] = {{0,0,0,0},{0,0,0,0}};

    for (int kt = 0; kt < SEQ / KT; ++kt) {
        __syncthreads();                       // prior PV reads of sK/sV/sP done
        #pragma unroll
        for (int i = 0; i < 8; ++i) {          // stage K tile
            int u = tid + 256 * i;
            int row = u >> 4, dg = u & 15;
            f32x4 v = *(const f32x4*)(Kh + (size_t)(kt * KT + row) * DH + dg * 4);
            bf16x4 b;
            b[0] = (__bf16)v[0]; b[1] = (__bf16)v[1]; b[2] = (__bf16)v[2]; b[3] = (__bf16)v[3];
            *(bf16x4*)(sK + row * KS + dg * 4) = b;
        }
        #pragma unroll
        for (int i = 0; i < 2; ++i) {          // stage V^T (4x4 micro-transpose)
            int u = tid + 256 * i;
            int kb = u & 31, db = u >> 5;
            int k0 = kb * 4, d0 = db * 4;
            f32x4 v0 = *(const f32x4*)(Vh + (size_t)(kt * KT + k0 + 0) * DH + d0);
            f32x4 v1 = *(const f32x4*)(Vh + (size_t)(kt * KT + k0 + 1) * DH + d0);
            f32x4 v2 = *(const f32x4*)(Vh + (size_t)(kt * KT + k0 + 2) * DH + d0);
            f32x4 v3 = *(const f32x4*)(Vh + (size_t)(kt * KT + k0 + 3) * DH + d0);
            #pragma unroll
            for (int jj = 0; jj < 4; ++jj) {
                bf16x4 b;
                b[0] = (__bf16)v0[jj]; b[1] = (__bf16)v1[jj];
                b[2] = (__bf16)v2[jj]; b[3] = (__bf16)v3[jj];
                *(bf16x4*)(sV + (d0 + jj) * VS + k0) = b;
            }
        }
        __syncthreads();

        f32x4 acc[4] = {{0,0,0,0},{0,0,0,0},{0,0,0,0},{0,0,0,0}};
        #pragma unroll
        for (int ks = 0; ks < 2; ++ks) {
            bf16x8 afrag = *(const bf16x8*)(sQ + (qt * 16 + lm) * KS + ks * 32 + lq * 8);
            #pragma unroll
            for (int c = 0; c < 4; ++c) {
                bf16x8 bfrag = *(const bf16x8*)(sK + ((ch * 4 + c) * 16 + lm) * KS + ks * 32 + lq * 8);
                acc[c] = __builtin_amdgcn_mfma_f32_16x16x32_bf16(afrag, bfrag, acc[c], 0, 0, 0);
            }
        }
        const int colg = kt * KT + ch * 64 + lm;   // global key col
        const int colt = ch * 64 + lm;             // tile-local key col
        #pragma unroll
        for (int r = 0; r < 4; ++r) {
            const float* brow = bias + (size_t)(rowg + r) * SEQ + colg;
            float* arow = attnh + (size_t)(rowg + r) * SEQ + colg;
            float il = linv[r], mf = mfin[r];
            #pragma unroll
            for (int c = 0; c < 4; ++c) {
                float x = acc[c][r] * scale + brow[c * 16];
                float p = __expf(x - mf) * il;     // normalized attn weight
                arow[c * 16] = p;
                sP[(qt * 16 + lq * 4 + r) * PS + colt + c * 16] = (__bf16)p;
            }
        }
        __syncthreads();                       // sP complete (cross-wave halves)

        #pragma unroll
        for (int ks = 0; ks < 4; ++ks) {
            bf16x8 afrag = *(const bf16x8*)(sP + (qt * 16 + lm) * PS + ks * 32 + lq * 8);
            #pragma unroll
            for (int c = 0; c < 2; ++c) {
                bf16x8 bfrag = *(const bf16x8*)(sV + ((dtb + c) * 16 + lm) * VS + ks * 32 + lq * 8);
                oacc[c] = __builtin_amdgcn_mfma_f32_16x16x32_bf16(afrag, bfrag, oacc[c], 0, 0, 0);
            }
        }
    }

    // ---- epilogue: out ----
    #pragma unroll
    for (int c = 0; c < 2; ++c)
        #pragma unroll
        for (int r = 0; r < 4; ++r)
            outh[(size_t)(rowg + r) * DH + (dtb + c) * 16 + lm] = oacc[c][r];
}

extern "C" void kernel_launch(void* const* d_in, const int* in_sizes, int n_in,
                              void* d_out, int out_size, void* d_ws, size_t ws_size,
                              hipStream_t stream) {
    const float* Q    = (const float*)d_in[0];
    const float* K    = (const float*)d_in[1];
    const float* V    = (const float*)d_in[2];
    const float* bias = (const float*)d_in[3];
    float* out  = (float*)d_out;
    float* attn = (float*)d_out + 4 * 16 * 1024 * 64;
    dim3 grid(64 * (SEQ / QR));
    dim3 block(256);
    attn_flash_kernel<<<grid, block, 0, stream>>>(Q, K, V, bias, out, attn);
}